// Round 4
// baseline (201.561 us; speedup 1.0000x reference)
//
#include <hip/hip_runtime.h>
#include <hip/hip_bf16.h>
#include <stdint.h>

#define B_ 4
#define M_ 1024
#define N_ 2048
#define D_ 1024
#define H_ 16
#define DH_ 64
#define NT 64
#define PITCH 72 // LDS row pitch in bf16: 144B, 16B-aligned

typedef __bf16 bf16_t;
typedef __attribute__((ext_vector_type(8))) __bf16 bf16x8;
typedef __attribute__((ext_vector_type(4))) float f32x4;

static __device__ __forceinline__ float silu_f(float x) {
  return x / (1.0f + __expf(-x));
}

// ---- K1: K' = L2norm(silu(kv heads)) -> kp[bh][n][d]. Fully coalesced reads
//      (wave reads 1KB contiguous per inst). grid B*N/4 blocks x 256.
__global__ __launch_bounds__(256) void prep_k_kernel(
    const float* __restrict__ kv, bf16_t* __restrict__ kp) {
  const int w = threadIdx.x >> 6, lane = threadIdx.x & 63;
  const int row = blockIdx.x * 4 + w;
  const int b = row >> 11, n = row & (N_ - 1);
  const float* src = kv + (size_t)row * D_;
  #pragma unroll
  for (int i = 0; i < 4; ++i) {
    float4 v = *(const float4*)(src + i * 256 + lane * 4);
    float s0 = silu_f(v.x), s1 = silu_f(v.y), s2 = silu_f(v.z), s3 = silu_f(v.w);
    float ss = s0 * s0 + s1 * s1 + s2 * s2 + s3 * s3;
    ss += __shfl_xor(ss, 1); ss += __shfl_xor(ss, 2);
    ss += __shfl_xor(ss, 4); ss += __shfl_xor(ss, 8);
    const float inv = 1.0f / fmaxf(sqrtf(ss), 1e-6f);
    const int h = i * 4 + (lane >> 4);
    union { bf16_t b4[4]; uint2 u; } pk;
    pk.b4[0] = (bf16_t)(s0 * inv); pk.b4[1] = (bf16_t)(s1 * inv);
    pk.b4[2] = (bf16_t)(s2 * inv); pk.b4[3] = (bf16_t)(s3 * inv);
    *(uint2*)(kp + ((size_t)(b * H_ + h) * N_ + n) * DH_ + (lane & 15) * 4) = pk.u;
  }
}

// ---- K2: Vt = kv heads transposed -> vt[bh][d][n] (bf16), via LDS tile.
//      grid: b(4) x nt(8) x h(16) = 512 blocks x 256.
__global__ __launch_bounds__(256) void prep_v_kernel(
    const float* __restrict__ kv, bf16_t* __restrict__ vt) {
  __shared__ __align__(16) bf16_t Vt2[256][68];
  const int bx = blockIdx.x;
  const int h = bx & 15, nt = (bx >> 4) & 7, b = bx >> 7;
  const int n0 = nt * 256;
  const int tid = threadIdx.x;
  #pragma unroll
  for (int it = 0; it < 16; ++it) {
    const int r = it * 16 + (tid >> 4);
    const int c = (tid & 15) * 4;
    float4 v = *(const float4*)(kv + ((size_t)(b * N_ + n0 + r)) * D_ + h * DH_ + c);
    union { bf16_t b4[4]; uint2 u; } pk;
    pk.b4[0] = (bf16_t)v.x; pk.b4[1] = (bf16_t)v.y;
    pk.b4[2] = (bf16_t)v.z; pk.b4[3] = (bf16_t)v.w;
    *(uint2*)&Vt2[r][c] = pk.u;
  }
  __syncthreads();
  const size_t bh = (size_t)(b * H_ + h);
  #pragma unroll
  for (int pass = 0; pass < 4; ++pass) {
    const int d = pass * 16 + (tid >> 4);
    const int nst = (tid & 15) * 16;
    union { bf16_t bs[16]; uint4 u[2]; } pk;
    #pragma unroll
    for (int kk = 0; kk < 16; ++kk) pk.bs[kk] = Vt2[nst + kk][d];
    uint4* dst = (uint4*)(vt + (bh * DH_ + d) * N_ + n0 + nst);
    dst[0] = pk.u[0]; dst[1] = pk.u[1];
  }
}

// ---- K3: mask bits via ballot. 128 words, one wave each. grid 32 x 256.
__global__ __launch_bounds__(256) void prep_mask_kernel(
    const int* __restrict__ kv_mask, unsigned long long* __restrict__ mb) {
  const int gw = (blockIdx.x * 256 + threadIdx.x) >> 6;
  const int lane = threadIdx.x & 63;
  unsigned long long m = __ballot(kv_mask[gw * 64 + lane] != 0);
  if (lane == 0) mb[gw] = m;
}

// ---- attn: flash cross-attention. 4 waves x 32 Q-rows, S^T orientation,
//      in-register P transform (no Ps/Qs LDS). NS = n-split factor.
template <int NS>
__global__ __launch_bounds__(256, 4) void attn_kernel(
    const float* __restrict__ q, const bf16_t* __restrict__ kp,
    const bf16_t* __restrict__ vt, const unsigned long long* __restrict__ mb,
    float* __restrict__ out, float* __restrict__ opart, float* __restrict__ lbuf) {
  __shared__ __align__(16) bf16_t Ks[NT][PITCH];
  __shared__ __align__(16) bf16_t Vs[DH_][PITCH];

  const int tid = threadIdx.x;
  const int w = tid >> 6, lane = tid & 63;
  const int l15 = lane & 15, quad = lane >> 4;
  const int bx = blockIdx.x;
  const int ns  = (NS == 2) ? (bx & 1) : 0;
  const int mt8 = (NS == 2) ? ((bx >> 1) & 7) : (bx & 7);
  const int bh  = (NS == 2) ? (bx >> 4) : (bx >> 3);
  const int m0 = mt8 * 128;
  const int b = bh >> 4, h = bh & 15;

  // Q fragments direct from global: rows w*32 + mt*16 + l15, silu+L2norm.
  bf16x8 qa[2][2];
  #pragma unroll
  for (int mt = 0; mt < 2; ++mt) {
    const float* qrow =
        q + ((size_t)(b * M_ + m0 + w * 32 + mt * 16 + l15)) * D_ + h * DH_;
    float vals[16];
    float ss = 0.f;
    #pragma unroll
    for (int kc = 0; kc < 2; ++kc) {
      float4 a = *(const float4*)(qrow + kc * 32 + quad * 8);
      float4 c4 = *(const float4*)(qrow + kc * 32 + quad * 8 + 4);
      vals[kc * 8 + 0] = silu_f(a.x);  vals[kc * 8 + 1] = silu_f(a.y);
      vals[kc * 8 + 2] = silu_f(a.z);  vals[kc * 8 + 3] = silu_f(a.w);
      vals[kc * 8 + 4] = silu_f(c4.x); vals[kc * 8 + 5] = silu_f(c4.y);
      vals[kc * 8 + 6] = silu_f(c4.z); vals[kc * 8 + 7] = silu_f(c4.w);
    }
    #pragma unroll
    for (int i = 0; i < 16; ++i) ss += vals[i] * vals[i];
    ss += __shfl_xor(ss, 16); ss += __shfl_xor(ss, 32);  // reduce across quads
    const float inv = 1.0f / fmaxf(sqrtf(ss), 1e-6f);
    #pragma unroll
    for (int kc = 0; kc < 2; ++kc) {
      union { bf16_t b8[8]; bf16x8 v; } pq;
      #pragma unroll
      for (int i = 0; i < 8; ++i) pq.b8[i] = (bf16_t)(vals[kc * 8 + i] * inv);
      qa[mt][kc] = pq.v;
    }
  }

  f32x4 o[2][4];
  float lsum[2] = {0.f, 0.f};
  #pragma unroll
  for (int mt = 0; mt < 2; ++mt)
    #pragma unroll
    for (int jd = 0; jd < 4; ++jd) o[mt][jd] = (f32x4){0.f, 0.f, 0.f, 0.f};

  const bf16_t* kpb = kp + ((size_t)bh * N_ + ns * (N_ / NS)) * DH_;
  const bf16_t* vtb = vt + (size_t)bh * DH_ * N_ + ns * (N_ / NS);
  const unsigned long long* mrow = mb + b * (N_ / 64) + ns * (N_ / NS / 64);
  const int iters = (N_ / NS) / NT;

  for (int t = 0; t < iters; ++t) {
    // stage K' [n][d] and V^T [d][n] tiles (2 bf16x8 per thread per array)
    #pragma unroll
    for (int it2 = 0; it2 < 2; ++it2) {
      const int slot = tid + it2 * 256;
      const int rr = slot >> 3, c8 = slot & 7;
      *(bf16x8*)&Ks[rr][c8 * 8] =
          *(const bf16x8*)(kpb + ((size_t)(t * NT + rr)) * DH_ + c8 * 8);
      *(bf16x8*)&Vs[rr][c8 * 8] =
          *(const bf16x8*)(vtb + (size_t)rr * N_ + t * NT + c8 * 8);
    }
    __syncthreads();
    const unsigned long long mk = mrow[t];

    // S^T = K' Q'^T : A=kb (rows n), B=qa (cols m). C: row n=quad*4+r+16j, col m=l15.
    f32x4 s[2][4];
    #pragma unroll
    for (int mt = 0; mt < 2; ++mt)
      #pragma unroll
      for (int j = 0; j < 4; ++j) s[mt][j] = (f32x4){0.f, 0.f, 0.f, 0.f};
    #pragma unroll
    for (int kc = 0; kc < 2; ++kc)
      #pragma unroll
      for (int j = 0; j < 4; ++j) {
        bf16x8 kbv = *(const bf16x8*)&Ks[j * 16 + l15][kc * 32 + quad * 8];
        s[0][j] = __builtin_amdgcn_mfma_f32_16x16x32_bf16(kbv, qa[0][kc], s[0][j], 0, 0, 0);
        s[1][j] = __builtin_amdgcn_mfma_f32_16x16x32_bf16(kbv, qa[1][kc], s[1][j], 0, 0, 0);
      }

    // fixed-max softmax (|s|<=1 since unit vectors): p = exp(s/8 - 1/8), 0 if masked.
    // Then in-register transform: P^T C-layout -> A-fragment P[m=l15][n=quad*8+i].
    bf16x8 pb[2][2];
    #pragma unroll
    for (int mt = 0; mt < 2; ++mt) {
      uint32_t pk[4][2];
      #pragma unroll
      for (int j = 0; j < 4; ++j)
        #pragma unroll
        for (int rp = 0; rp < 2; ++rp) {
          const int nb = 16 * j + quad * 4 + rp * 2;
          const bool m0k = (mk >> nb) & 1ull;
          const bool m1k = (mk >> (nb + 1)) & 1ull;
          float p0 = m0k ? 0.f : __expf(s[mt][j][rp * 2] * 0.125f - 0.125f);
          float p1 = m1k ? 0.f : __expf(s[mt][j][rp * 2 + 1] * 0.125f - 0.125f);
          lsum[mt] += p0 + p1;
          union { bf16_t b2[2]; uint32_t u; } t2;
          t2.b2[0] = (bf16_t)p0; t2.b2[1] = (bf16_t)p1;
          pk[j][rp] = t2.u;
        }
      const int src0 = l15 + 32 * (quad & 1);
      const int src1 = src0 + 16;
      const bool hi = quad >= 2;
      #pragma unroll
      for (int kc = 0; kc < 2; ++kc) {
        uint32_t a0 = __shfl(pk[kc * 2][0], src0), a1 = __shfl(pk[kc * 2 + 1][0], src0);
        uint32_t b0 = __shfl(pk[kc * 2][1], src0), b1 = __shfl(pk[kc * 2 + 1][1], src0);
        uint32_t c0 = __shfl(pk[kc * 2][0], src1), c1 = __shfl(pk[kc * 2 + 1][0], src1);
        uint32_t d0 = __shfl(pk[kc * 2][1], src1), d1 = __shfl(pk[kc * 2 + 1][1], src1);
        union { uint32_t u[4]; bf16x8 v; } pbv;
        pbv.u[0] = hi ? a1 : a0; pbv.u[1] = hi ? b1 : b0;
        pbv.u[2] = hi ? c1 : c0; pbv.u[3] = hi ? d1 : d0;
        pb[mt][kc] = pbv.v;
      }
    }

    // O += P V : A=pb, B=V[n][d] read from Vs[d][n]. C: row m=quad*4+r, col d=l15+16jd.
    #pragma unroll
    for (int kc = 0; kc < 2; ++kc)
      #pragma unroll
      for (int jd = 0; jd < 4; ++jd) {
        bf16x8 vbv = *(const bf16x8*)&Vs[jd * 16 + l15][kc * 32 + quad * 8];
        o[0][jd] = __builtin_amdgcn_mfma_f32_16x16x32_bf16(pb[0][kc], vbv, o[0][jd], 0, 0, 0);
        o[1][jd] = __builtin_amdgcn_mfma_f32_16x16x32_bf16(pb[1][kc], vbv, o[1][jd], 0, 0, 0);
      }
    __syncthreads();
  }

  // l: reduce across the 4 quads sharing m=l15
  #pragma unroll
  for (int mt = 0; mt < 2; ++mt) {
    lsum[mt] += __shfl_xor(lsum[mt], 16);
    lsum[mt] += __shfl_xor(lsum[mt], 32);
  }

  if (NS == 2) {
    float* dst = ns ? opart : out;
    #pragma unroll
    for (int mt = 0; mt < 2; ++mt) {
      const int mrow_ = m0 + w * 32 + mt * 16;
      if (quad == 0)
        lbuf[(size_t)(ns * 64 + bh) * M_ + mrow_ + l15] = lsum[mt];
      #pragma unroll
      for (int r = 0; r < 4; ++r) {
        const int m = mrow_ + quad * 4 + r;
        const size_t base = ((size_t)(b * M_ + m)) * D_ + h * DH_ + l15;
        #pragma unroll
        for (int jd = 0; jd < 4; ++jd)
          dst[base + jd * 16] = o[mt][jd][r];
      }
    }
  } else {
    #pragma unroll
    for (int mt = 0; mt < 2; ++mt) {
      float lv[4];
      #pragma unroll
      for (int r = 0; r < 4; ++r) lv[r] = __shfl(lsum[mt], quad * 4 + r);
      #pragma unroll
      for (int r = 0; r < 4; ++r) {
        const float invl = lv[r] > 0.f ? 1.0f / lv[r] : 0.f;
        const int m = m0 + w * 32 + mt * 16 + quad * 4 + r;
        const size_t base = ((size_t)(b * M_ + m)) * D_ + h * DH_ + l15;
        #pragma unroll
        for (int jd = 0; jd < 4; ++jd)
          out[base + jd * 16] = o[mt][jd][r] * invl;
      }
    }
  }
}

// ---- combine (NS=2): out = (out + opart) / (l0 + l1)
__global__ __launch_bounds__(256) void combine_kernel(
    float* __restrict__ out, const float* __restrict__ opart,
    const float* __restrict__ lbuf) {
  const size_t gi = ((size_t)blockIdx.x * 256 + threadIdx.x) * 4;
  const int d4 = gi & (D_ - 1);
  const int m = (gi >> 10) & (M_ - 1);
  const int b = gi >> 20;
  const int h = d4 >> 6;
  const int bh = b * H_ + h;
  const float l = lbuf[(size_t)bh * M_ + m] + lbuf[(size_t)(64 + bh) * M_ + m];
  const float invl = l > 0.f ? 1.0f / l : 0.f;
  float4 a = *(const float4*)(out + gi);
  float4 c = *(const float4*)(opart + gi);
  float4 r = {(a.x + c.x) * invl, (a.y + c.y) * invl,
              (a.z + c.z) * invl, (a.w + c.w) * invl};
  *(float4*)(out + gi) = r;
}

extern "C" void kernel_launch(void* const* d_in, const int* in_sizes, int n_in,
                              void* d_out, int out_size, void* d_ws, size_t ws_size,
                              hipStream_t stream) {
  const float* q = (const float*)d_in[0];
  const float* kv = (const float*)d_in[1];
  const int* kv_mask = (const int*)d_in[2];
  float* out = (float*)d_out;

  // ws layout: kp 16MB | vt 16MB | mb 4KB | lbuf 512KB | opart 16MB
  const size_t kp_sz = (size_t)B_ * H_ * N_ * DH_ * sizeof(bf16_t);   // 16 MB
  const size_t vt_sz = kp_sz;                                          // 16 MB
  const size_t mb_sz = 4096;
  const size_t lb_sz = (size_t)2 * 64 * M_ * sizeof(float);            // 512 KB
  const size_t op_sz = (size_t)B_ * M_ * D_ * sizeof(float);           // 16 MB
  char* p = (char*)d_ws;
  bf16_t* kp = (bf16_t*)p;
  bf16_t* vt = (bf16_t*)(p + kp_sz);
  unsigned long long* mb = (unsigned long long*)(p + kp_sz + vt_sz);
  float* lbuf = (float*)(p + kp_sz + vt_sz + mb_sz);
  float* opart = (float*)(p + kp_sz + vt_sz + mb_sz + lb_sz);
  const size_t need2 = kp_sz + vt_sz + mb_sz + lb_sz + op_sz;

  prep_k_kernel<<<B_ * N_ / 4, 256, 0, stream>>>(kv, kp);
  prep_v_kernel<<<B_ * 8 * H_, 256, 0, stream>>>(kv, vt);
  prep_mask_kernel<<<B_ * (N_ / 64) / 4, 256, 0, stream>>>(kv_mask, mb);

  if (ws_size >= need2) {
    attn_kernel<2><<<64 * 8 * 2, 256, 0, stream>>>(q, kp, vt, mb, out, opart, lbuf);
    combine_kernel<<<(B_ * M_ * D_) / 4 / 256, 256, 0, stream>>>(out, opart, lbuf);
  } else {
    attn_kernel<1><<<64 * 8, 256, 0, stream>>>(q, kp, vt, mb, out, opart, lbuf);
  }
}